// Round 8
// baseline (208.133 us; speedup 1.0000x reference)
//
#include <hip/hip_runtime.h>
#include <hip/hip_bf16.h>

#define BATCH 4
#define SEQ   2048
#define DIM   1024
#define NHEAD 16
#define HDIM  64

typedef __bf16    bf16x8 __attribute__((ext_vector_type(8)));
typedef float     f32x16 __attribute__((ext_vector_type(16)));
typedef unsigned  u32;

__device__ __forceinline__ unsigned short f2bfu(float x) {
  union { __hip_bfloat16 b; unsigned short u; } c; c.b = __float2bfloat16(x); return c.u;
}
__device__ __forceinline__ u32 cvtpk(float lo, float hi) {
  u32 r; asm("v_cvt_pk_bf16_f32 %0, %1, %2" : "=v"(r) : "v"(lo), "v"(hi)); return r;
}
__device__ __forceinline__ int swz4(int row) {
  return ((row & 7) ^ ((row >> 3) & 7)) << 2;
}

// async 16B global->LDS (linear LDS dest: wave-uniform base + lane*16)
#define GLDS16(GP, LP)                                                         \
  __builtin_amdgcn_global_load_lds(                                            \
      (const __attribute__((address_space(1))) void*)(GP),                     \
      (__attribute__((address_space(3))) void*)(LP), 16, 0, 0)

// ---------------------------------------------------------------------------
// Weight transpose+convert: Wt[n][k] = bf16(W[k][n]). 64x64 tile per block.
// ---------------------------------------------------------------------------
__global__ __launch_bounds__(256)
void wtrans(const float* __restrict__ w0, const float* __restrict__ w1,
            const float* __restrict__ w2,
            __hip_bfloat16* __restrict__ t0, __hip_bfloat16* __restrict__ t1,
            __hip_bfloat16* __restrict__ t2)
{
  __shared__ float T[64][68];
  const int mat  = blockIdx.x >> 8;
  const int tile = blockIdx.x & 255;
  const float* W = mat == 0 ? w0 : (mat == 1 ? w1 : w2);
  __hip_bfloat16* Wt = mat == 0 ? t0 : (mat == 1 ? t1 : t2);
  const int k0 = (tile >> 4) * 64, n0 = (tile & 15) * 64;
  const int tid = threadIdx.x;
  const int r = tid >> 2, cq = (tid & 3) * 16;
  #pragma unroll
  for (int j = 0; j < 4; ++j) {
    const float4 v = *reinterpret_cast<const float4*>(&W[(size_t)(k0 + r) * DIM + n0 + cq + j * 4]);
    T[r][cq + j * 4 + 0] = v.x; T[r][cq + j * 4 + 1] = v.y;
    T[r][cq + j * 4 + 2] = v.z; T[r][cq + j * 4 + 3] = v.w;
  }
  __syncthreads();
  u32 o[8];
  #pragma unroll
  for (int j = 0; j < 8; ++j)
    o[j] = cvtpk(T[cq + 2 * j][r], T[cq + 2 * j + 1][r]);
  *reinterpret_cast<uint4*>(&Wt[(size_t)(n0 + r) * DIM + k0 + cq + 0]) = make_uint4(o[0], o[1], o[2], o[3]);
  *reinterpret_cast<uint4*>(&Wt[(size_t)(n0 + r) * DIM + k0 + cq + 8]) = make_uint4(o[4], o[5], o[6], o[7]);
}

// ---------------------------------------------------------------------------
// 2-phase double-buffered GEMM: C[M,1024] = A[M,1024] * Wt^T + bias.
// LDS always holds bf16 (A fp32 -> reg-staged cvt; A bf16 -> GLDS16 direct).
// Stage t+1 issued BEFORE compute of t; ONE barrier per K-step (T3 minimum).
// 128x128 tile, BK=64, 4 waves 2x2 of 64x64, 32x32x16 MFMA. LDS 64KB static.
// ---------------------------------------------------------------------------
template<typename TIN, typename TOUT, int NSEG>
__global__ __launch_bounds__(256, 2)
void gemm2ph(const TIN* __restrict__ A0, const TIN* __restrict__ A1, const TIN* __restrict__ A2,
             const __hip_bfloat16* __restrict__ W0, const __hip_bfloat16* __restrict__ W1,
             const __hip_bfloat16* __restrict__ W2,
             const float* __restrict__ b0, const float* __restrict__ b1, const float* __restrict__ b2,
             TOUT* __restrict__ C0, TOUT* __restrict__ C1, TOUT* __restrict__ C2)
{
  __shared__ __align__(16) u32 As32[2][128][32];   // bf16 [row][k-pairs], swizzled
  __shared__ __align__(16) u32 Bs32[2][128][32];   // bf16 [col][k-pairs], swizzled

  constexpr bool AF32 = (sizeof(TIN) == 4);
  constexpr int K = 1024, NT = 16;

  const int seg = (NSEG == 1) ? 0 : (blockIdx.x >> 9);
  const int idb = (NSEG == 1) ? blockIdx.x : (blockIdx.x & 511);
  const TIN* A = seg == 0 ? A0 : (seg == 1 ? A1 : A2);
  const __hip_bfloat16* Wt = seg == 0 ? W0 : (seg == 1 ? W1 : W2);
  const float* bias = seg == 0 ? b0 : (seg == 1 ? b1 : b2);
  TOUT* C = seg == 0 ? C0 : (seg == 1 ? C1 : C2);

  const int xcd = idb & 7, rr = idb >> 3;
  const int bx = rr & 7, by = xcd + 8 * (rr >> 3);
  const int m0 = by * 128, n0 = bx * 128;

  const int tid = threadIdx.x, lane = tid & 63, w = tid >> 6;
  const int l31 = lane & 31, hi = lane >> 5;
  const int wm = w >> 1, wn = w & 1;

  f32x16 acc[2][2] = {};

  // ---- B staging sources (pre-swizzled global addr, linear GLDS dest) ----
  const __hip_bfloat16* bptr[4];
  #pragma unroll
  for (int i = 0; i < 4; ++i) {
    const int off = (w * 4 + i) * 1024 + lane * 16;
    const int r = off >> 7;
    const int s = (off >> 4) & 7;
    bptr[i] = Wt + (size_t)(n0 + r) * K + (s ^ (r & 7)) * 8;
  }
  // ---- A staging sources ----
  const TIN* aptr[4];               // bf16 path (GLDS16)
  const int arow = tid >> 3;        // fp32 path (reg-stage): rows arow + 32p
  const int acb  = (tid & 7) * 8;   // fp32 col base
  #pragma unroll
  for (int i = 0; i < 4; ++i) {
    if constexpr (!AF32) {
      const int off = (w * 4 + i) * 1024 + lane * 16;
      const int r = off >> 7;
      const int s = (off >> 4) & 7;
      aptr[i] = A + (size_t)(m0 + r) * K + (s ^ (r & 7)) * 8;
    } else {
      aptr[i] = nullptr;
    }
  }

  float4 ar[4][2];   // fp32 A in-flight registers

  auto loadA_f32 = [&](int t) {
    #pragma unroll
    for (int p = 0; p < 4; ++p) {
      const float* ap = (const float*)A + (size_t)(m0 + arow + p * 32) * K + t * 64 + acb;
      ar[p][0] = *reinterpret_cast<const float4*>(ap);
      ar[p][1] = *reinterpret_cast<const float4*>(ap + 4);
    }
  };
  auto writeA_f32 = [&](int nxt) {
    #pragma unroll
    for (int p = 0; p < 4; ++p) {
      const int row = arow + p * 32;
      uint4 pk;
      pk.x = cvtpk(ar[p][0].x, ar[p][0].y);
      pk.y = cvtpk(ar[p][0].z, ar[p][0].w);
      pk.z = cvtpk(ar[p][1].x, ar[p][1].y);
      pk.w = cvtpk(ar[p][1].z, ar[p][1].w);
      *reinterpret_cast<uint4*>(&As32[nxt][row][((tid & 7) * 4) ^ ((row & 7) << 2)]) = pk;
    }
  };
  auto stageA_bf = [&](int nxt, int t) {
    #pragma unroll
    for (int i = 0; i < 4; ++i)
      GLDS16((const __hip_bfloat16*)aptr[i] + t * 64,
             (char*)As32 + nxt * 16384 + (w * 4 + i) * 1024);
  };
  auto stageB = [&](int nxt, int t) {
    #pragma unroll
    for (int i = 0; i < 4; ++i)
      GLDS16(bptr[i] + t * 64,
             (char*)Bs32 + nxt * 16384 + (w * 4 + i) * 1024);
  };

  // ---- t-invariant LDS read byte-offsets (bf16 layout for both A and B) ----
  int aoff[4][2], boff[4][2];
  #pragma unroll
  for (int kk = 0; kk < 4; ++kk) {
    #pragma unroll
    for (int mi = 0; mi < 2; ++mi) {
      const int r = wm * 64 + mi * 32 + l31;
      aoff[kk][mi] = r * 128 + (((kk * 2 + hi) ^ (r & 7)) << 4);
    }
    #pragma unroll
    for (int ni = 0; ni < 2; ++ni) {
      const int c = wn * 64 + ni * 32 + l31;
      boff[kk][ni] = c * 128 + (((kk * 2 + hi) ^ (c & 7)) << 4);
    }
  }

  // ---- prologue: stage tile 0 into buffer 0 ----
  if constexpr (AF32) { loadA_f32(0); writeA_f32(0); }
  else                { stageA_bf(0, 0); }
  stageB(0, 0);
  __syncthreads();

  for (int t = 0; t < NT; ++t) {
    const int cur = t & 1, nxt = cur ^ 1;

    // ---- issue stage of t+1 BEFORE compute (latency hides under MFMA) ----
    if (t + 1 < NT) {
      if constexpr (AF32) loadA_f32(t + 1);
      else                stageA_bf(nxt, t + 1);
      stageB(nxt, t + 1);
    }

    // ---- compute tile t ----
    const char* ab = (const char*)As32 + cur * 16384;
    const char* bb = (const char*)Bs32 + cur * 16384;
    #pragma unroll
    for (int kk = 0; kk < 4; ++kk) {
      bf16x8 af[2], bfv[2];
      #pragma unroll
      for (int mi = 0; mi < 2; ++mi)
        af[mi] = *reinterpret_cast<const bf16x8*>(ab + aoff[kk][mi]);
      #pragma unroll
      for (int ni = 0; ni < 2; ++ni)
        bfv[ni] = *reinterpret_cast<const bf16x8*>(bb + boff[kk][ni]);
      __builtin_amdgcn_s_setprio(1);
      #pragma unroll
      for (int mi = 0; mi < 2; ++mi)
        #pragma unroll
        for (int ni = 0; ni < 2; ++ni)
          acc[mi][ni] = __builtin_amdgcn_mfma_f32_32x32x16_bf16(af[mi], bfv[ni], acc[mi][ni], 0, 0, 0);
      __builtin_amdgcn_s_setprio(0);
    }

    // ---- fp32 A: convert + write into next buffer (after compute) ----
    if (t + 1 < NT) {
      if constexpr (AF32) writeA_f32(nxt);
    }
    __syncthreads();   // drains vmcnt (B GLDS) + lgkmcnt (A writes); publishes nxt
  }

  // ---- epilogue: D col = lane&31, row = (r&3) + 8*(r>>2) + 4*hi ----
  #pragma unroll
  for (int ni = 0; ni < 2; ++ni) {
    const int col = n0 + wn * 64 + ni * 32 + l31;
    const float bv = bias[col];
    #pragma unroll
    for (int mi = 0; mi < 2; ++mi) {
      #pragma unroll
      for (int g = 0; g < 4; ++g)
        #pragma unroll
        for (int e = 0; e < 4; ++e) {
          const int row = m0 + wm * 64 + mi * 32 + g * 8 + hi * 4 + e;
          const float val = acc[mi][ni][g * 4 + e] + bv;
          if constexpr (sizeof(TOUT) == 2)
            C[(size_t)row * DIM + col] = __float2bfloat16(val);
          else
            C[(size_t)row * DIM + col] = val;
        }
    }
  }
}

// ---------------------------------------------------------------------------
// Flash attention (round-7 verified: static-max softmax, QB=256, 512 blocks).
// ---------------------------------------------------------------------------
__global__ __launch_bounds__(256, 2)
void flash_attn(const __hip_bfloat16* __restrict__ Qb,
                const __hip_bfloat16* __restrict__ Kb,
                const __hip_bfloat16* __restrict__ Vb,
                __hip_bfloat16* __restrict__ Ob)
{
  __shared__ __align__(16) u32 Ks32[2][64][32];
  __shared__ __align__(16) u32 Vt32[2][64][32];

  const int id  = blockIdx.x;
  const int xcd = id & 7;
  const int r_  = id >> 3;
  const int qb  = r_ & 7;
  const int hh  = (r_ >> 3) & 1;
  const int b   = r_ >> 4;
  const int h   = xcd + 8 * hh;

  const int tid = threadIdx.x, lane = tid & 63, wv = tid >> 6;
  const int l31 = lane & 31, hi = lane >> 5;

  const size_t headoff = (size_t)h * HDIM;
  const int q0 = b * SEQ + qb * 256 + wv * 64;

  bf16x8 qf[2][4];
  #pragma unroll
  for (int qh = 0; qh < 2; ++qh)
    #pragma unroll
    for (int dk = 0; dk < 4; ++dk)
      qf[qh][dk] = *reinterpret_cast<const bf16x8*>(
        &Qb[(size_t)(q0 + qh * 32 + l31) * DIM + headoff + dk * 16 + hi * 8]);

  f32x16 accO[2][2] = {};
  float l_run[2] = {0.f, 0.f};

  const int skey = tid >> 2;
  const int sdq  = tid & 3;
  const int vkp  = tid >> 3;
  const int vdb  = tid & 7;
  const size_t kbase = (size_t)b * SEQ * DIM + headoff;

  uint4 kst[2], vst[2];
  auto load_t = [&](int t) {
    const int kb = t * 64;
    const __hip_bfloat16* kp_ = &Kb[kbase + (size_t)(kb + skey) * DIM + sdq * 16];
    kst[0] = *reinterpret_cast<const uint4*>(kp_);
    kst[1] = *reinterpret_cast<const uint4*>(kp_ + 8);
    const __hip_bfloat16* vp_ = &Vb[kbase + (size_t)(kb + vkp * 2) * DIM + vdb * 8];
    vst[0] = *reinterpret_cast<const uint4*>(vp_);
    vst[1] = *reinterpret_cast<const uint4*>(vp_ + DIM);
  };
  auto store_t = [&](int bb) {
    const int sk = swz4(skey);
    *reinterpret_cast<uint4*>(&Ks32[bb][skey][(sdq * 8 + 0) ^ sk]) = kst[0];
    *reinterpret_cast<uint4*>(&Ks32[bb][skey][(sdq * 8 + 4) ^ sk]) = kst[1];
    const unsigned short* a  = (const unsigned short*)&vst[0];
    const unsigned short* bv = (const unsigned short*)&vst[1];
    #pragma unroll
    for (int j = 0; j < 8; ++j) {
      const int row = vdb * 8 + j;
      Vt32[bb][row][vkp ^ swz4(row)] = (u32)a[j] | ((u32)bv[j] << 16);
    }
  };

  load_t(0); store_t(0); __syncthreads();

  const float C1 = 0.125f * 1.44269504f;

  for (int t = 0; t < SEQ / 64; ++t) {
    const int bb = t & 1;
    if (t < SEQ / 64 - 1) load_t(t + 1);

    f32x16 sacc[2][2] = {};
    __builtin_amdgcn_s_setprio(1);
    #pragma unroll
    for (int kt = 0; kt < 2; ++kt) {
      const int row = kt * 32 + l31;
      const int sk = swz4(row);
      #pragma unroll
      for (int dk = 0; dk < 4; ++dk) {
        bf16x8 kf = *reinterpret_cast<const bf16x8*>(&Ks32[bb][row][(dk * 8 + hi * 4) ^ sk]);
        sacc[0][kt] = __builtin_amdgcn_mfma_f32_32x32x16_bf16(kf, qf[0][dk], sacc[0][kt], 0, 0, 0);
        sacc[1][kt] = __builtin_amdgcn_mfma_f32_32x32x16_bf16(kf, qf[1][dk], sacc[1][kt], 0, 0, 0);
      }
    }
    __builtin_amdgcn_s_setprio(0);

    u32 pf[2][4][4];
    #pragma unroll
    for (int qh = 0; qh < 2; ++qh) {
      #pragma unroll
      for (int kt = 0; kt < 2; ++kt)
        #pragma unroll
        for (int r2 = 0; r2 < 16; ++r2)
          sacc[qh][kt][r2] = __builtin_amdgcn_exp2f(sacc[qh][kt][r2] * C1);

      f32x16 ps = sacc[qh][0] + sacc[qh][1];
      float s8[8];
      #pragma unroll
      for (int i = 0; i < 8; ++i) s8[i] = ps[i] + ps[i + 8];
      float rs = ((s8[0] + s8[1]) + (s8[2] + s8[3])) + ((s8[4] + s8[5]) + (s8[6] + s8[7]));
      rs += __shfl_xor(rs, 32);
      l_run[qh] += rs;

#define MAKE_PF(DST, P, B) do {                                            \
      u32 x1 = cvtpk(P[B+0], P[B+1]);                                      \
      u32 y1 = cvtpk(P[B+4], P[B+5]);                                      \
      u32 x2 = cvtpk(P[B+2], P[B+3]);                                      \
      u32 y2 = cvtpk(P[B+6], P[B+7]);                                      \
      auto s1 = __builtin_amdgcn_permlane32_swap(x1, y1, false, false);    \
      auto s2 = __builtin_amdgcn_permlane32_swap(x2, y2, false, false);    \
      DST[0] = (u32)s1[0]; DST[1] = (u32)s2[0];                            \
      DST[2] = (u32)s1[1]; DST[3] = (u32)s2[1];                            \
    } while (0)
      MAKE_PF(pf[qh][0], sacc[qh][0], 0);
      MAKE_PF(pf[qh][1], sacc[qh][0], 8);
      MAKE_PF(pf[qh][2], sacc[qh][1], 0);
      MAKE_PF(pf[qh][3], sacc[qh][1], 8);
#undef MAKE_PF
    }

    __builtin_amdgcn_s_setprio(1);
    #pragma unroll
    for (int dt = 0; dt < 2; ++dt) {
      const int row = dt * 32 + l31;
      const int sk = swz4(row);
      #pragma unroll
      for (int kf = 0; kf < 4; ++kf) {
        bf16x8 vf = *reinterpret_cast<const bf16x8*>(&Vt32[bb][row][(kf * 8 + hi * 4) ^ sk]);
        #pragma unroll
        for (int qh = 0; qh < 2; ++qh) {
          union { u32 u[4]; bf16x8 v; } pu;
          pu.u[0] = pf[qh][kf][0]; pu.u[1] = pf[qh][kf][1];
          pu.u[2] = pf[qh][kf][2]; pu.u[3] = pf[qh][kf][3];
          accO[qh][dt] = __builtin_amdgcn_mfma_f32_32x32x16_bf16(vf, pu.v, accO[qh][dt], 0, 0, 0);
        }
      }
    }
    __builtin_amdgcn_s_setprio(0);

    if (t < SEQ / 64 - 1) store_t(bb ^ 1);
    __syncthreads();
  }

  #pragma unroll
  for (int qh = 0; qh < 2; ++qh) {
    const float inv = 1.f / l_run[qh];
    const size_t rowbase = (size_t)(q0 + qh * 32 + l31) * DIM + headoff;
    #pragma unroll
    for (int dt = 0; dt < 2; ++dt)
      #pragma unroll
      for (int g = 0; g < 4; ++g) {
        ushort4 o;
        o.x = f2bfu(accO[qh][dt][g * 4 + 0] * inv);
        o.y = f2bfu(accO[qh][dt][g * 4 + 1] * inv);
        o.z = f2bfu(accO[qh][dt][g * 4 + 2] * inv);
        o.w = f2bfu(accO[qh][dt][g * 4 + 3] * inv);
        *reinterpret_cast<ushort4*>(&Ob[rowbase + dt * 32 + g * 8 + hi * 4]) = o;
      }
  }
}

// ---------------------------------------------------------------------------
extern "C" void kernel_launch(void* const* d_in, const int* in_sizes, int n_in,
                              void* d_out, int out_size, void* d_ws, size_t ws_size,
                              hipStream_t stream)
{
  const float* q  = (const float*)d_in[0];
  const float* k  = (const float*)d_in[1];
  const float* v  = (const float*)d_in[2];
  const float* wq = (const float*)d_in[3];
  const float* bq = (const float*)d_in[4];
  const float* wk = (const float*)d_in[5];
  const float* bk = (const float*)d_in[6];
  const float* wv = (const float*)d_in[7];
  const float* bv = (const float*)d_in[8];
  const float* wo = (const float*)d_in[9];
  const float* bo = (const float*)d_in[10];

  const size_t MN = (size_t)BATCH * SEQ * DIM;   // 8388608
  const size_t KK = (size_t)DIM * DIM;           // 1048576

  __hip_bfloat16* Qb = (__hip_bfloat16*)d_ws;
  __hip_bfloat16* Kb = Qb + MN;
  __hip_bfloat16* Vb = Kb + MN;
  __hip_bfloat16* S3 = Vb + MN;     // 4th 16MB slot
  __hip_bfloat16* WtQ = S3;         // weights live here until attention
  __hip_bfloat16* WtK = S3 + KK;
  __hip_bfloat16* WtV = S3 + 2 * KK;
  __hip_bfloat16* Ob  = S3;         // attention output overwrites Wt (dead)
  __hip_bfloat16* WtO = (__hip_bfloat16*)d_ws;  // into Qb slot after attention

  wtrans<<<768, 256, 0, stream>>>(wq, wk, wv, WtQ, WtK, WtV);

  gemm2ph<float, __hip_bfloat16, 3><<<1536, 256, 0, stream>>>(
      q, k, v, WtQ, WtK, WtV, bq, bk, bv, Qb, Kb, Vb);

  flash_attn<<<512, 256, 0, stream>>>(Qb, Kb, Vb, Ob);

  wtrans<<<256, 256, 0, stream>>>(wo, wo, wo, WtO, WtO, WtO);

  gemm2ph<__hip_bfloat16, float, 1><<<512, 256, 0, stream>>>(
      Ob, Ob, Ob, WtO, WtO, WtO, bo, bo, bo,
      (float*)d_out, (float*)d_out, (float*)d_out);
}

// Round 9
// 200.805 us; speedup vs baseline: 1.0365x; 1.0365x over previous
//
#include <hip/hip_runtime.h>
#include <hip/hip_bf16.h>

#define BATCH 4
#define SEQ   2048
#define DIM   1024
#define NHEAD 16
#define HDIM  64

typedef __bf16    bf16x8 __attribute__((ext_vector_type(8)));
typedef float     f32x16 __attribute__((ext_vector_type(16)));
typedef unsigned  u32;

__device__ __forceinline__ unsigned short f2bfu(float x) {
  union { __hip_bfloat16 b; unsigned short u; } c; c.b = __float2bfloat16(x); return c.u;
}
__device__ __forceinline__ u32 cvtpk(float lo, float hi) {
  u32 r; asm("v_cvt_pk_bf16_f32 %0, %1, %2" : "=v"(r) : "v"(lo), "v"(hi)); return r;
}
__device__ __forceinline__ int swz4(int row) {
  return ((row & 7) ^ ((row >> 3) & 7)) << 2;
}

// async 16B global->LDS (linear LDS dest: wave-uniform base + lane*16)
#define GLDS16(GP, LP)                                                         \
  __builtin_amdgcn_global_load_lds(                                            \
      (const __attribute__((address_space(1))) void*)(GP),                     \
      (__attribute__((address_space(3))) void*)(LP), 16, 0, 0)

// ---------------------------------------------------------------------------
// Weight transpose+convert: Wt[n][k] = bf16(W[k][n]). 64x64 tile per block.
// ---------------------------------------------------------------------------
__global__ __launch_bounds__(256)
void wtrans(const float* __restrict__ w0, const float* __restrict__ w1,
            const float* __restrict__ w2,
            __hip_bfloat16* __restrict__ t0, __hip_bfloat16* __restrict__ t1,
            __hip_bfloat16* __restrict__ t2)
{
  __shared__ float T[64][68];
  const int mat  = blockIdx.x >> 8;
  const int tile = blockIdx.x & 255;
  const float* W = mat == 0 ? w0 : (mat == 1 ? w1 : w2);
  __hip_bfloat16* Wt = mat == 0 ? t0 : (mat == 1 ? t1 : t2);
  const int k0 = (tile >> 4) * 64, n0 = (tile & 15) * 64;
  const int tid = threadIdx.x;
  const int r = tid >> 2, cq = (tid & 3) * 16;
  #pragma unroll
  for (int j = 0; j < 4; ++j) {
    const float4 v = *reinterpret_cast<const float4*>(&W[(size_t)(k0 + r) * DIM + n0 + cq + j * 4]);
    T[r][cq + j * 4 + 0] = v.x; T[r][cq + j * 4 + 1] = v.y;
    T[r][cq + j * 4 + 2] = v.z; T[r][cq + j * 4 + 3] = v.w;
  }
  __syncthreads();
  u32 o[8];
  #pragma unroll
  for (int j = 0; j < 8; ++j)
    o[j] = cvtpk(T[cq + 2 * j][r], T[cq + 2 * j + 1][r]);
  *reinterpret_cast<uint4*>(&Wt[(size_t)(n0 + r) * DIM + k0 + cq + 0]) = make_uint4(o[0], o[1], o[2], o[3]);
  *reinterpret_cast<uint4*>(&Wt[(size_t)(n0 + r) * DIM + k0 + cq + 8]) = make_uint4(o[4], o[5], o[6], o[7]);
}

// ---------------------------------------------------------------------------
// 1-phase GEMM, bf16-only 32KB LDS (single-buffered) -> 4 blocks/CU.
// fp32 A: reg-stage (loads issued before compute, cvt+ds_write after barrier).
// bf16 A: GLDS16 direct. B (bf16 Wt[N][K]): GLDS16, pre-swizzled source.
// 128x128 tile, BK=64, 4 waves 2x2 of 64x64, 32x32x16 MFMA.
// ---------------------------------------------------------------------------
template<typename TIN, typename TOUT, int NSEG>
__global__ __launch_bounds__(256, 2)
void gemm1ph(const TIN* __restrict__ A0, const TIN* __restrict__ A1, const TIN* __restrict__ A2,
             const __hip_bfloat16* __restrict__ W0, const __hip_bfloat16* __restrict__ W1,
             const __hip_bfloat16* __restrict__ W2,
             const float* __restrict__ b0, const float* __restrict__ b1, const float* __restrict__ b2,
             TOUT* __restrict__ C0, TOUT* __restrict__ C1, TOUT* __restrict__ C2)
{
  __shared__ __align__(16) u32 As32[128][32];   // bf16 [row][k-pairs], swizzled (16KB)
  __shared__ __align__(16) u32 Bs32[128][32];   // bf16 [col][k-pairs], swizzled (16KB)

  constexpr bool AF32 = (sizeof(TIN) == 4);
  constexpr int K = 1024, NT = 16;

  const int seg = (NSEG == 1) ? 0 : (blockIdx.x >> 9);
  const int idb = (NSEG == 1) ? blockIdx.x : (blockIdx.x & 511);
  const TIN* A = seg == 0 ? A0 : (seg == 1 ? A1 : A2);
  const __hip_bfloat16* Wt = seg == 0 ? W0 : (seg == 1 ? W1 : W2);
  const float* bias = seg == 0 ? b0 : (seg == 1 ? b1 : b2);
  TOUT* C = seg == 0 ? C0 : (seg == 1 ? C1 : C2);

  const int xcd = idb & 7, rr = idb >> 3;
  const int bx = rr & 7, by = xcd + 8 * (rr >> 3);
  const int m0 = by * 128, n0 = bx * 128;

  const int tid = threadIdx.x, lane = tid & 63, w = tid >> 6;
  const int l31 = lane & 31, hi = lane >> 5;
  const int wm = w >> 1, wn = w & 1;

  f32x16 acc[2][2] = {};

  // ---- B staging sources (pre-swizzled global addr, linear GLDS dest) ----
  const __hip_bfloat16* bptr[4];
  #pragma unroll
  for (int i = 0; i < 4; ++i) {
    const int off = (w * 4 + i) * 1024 + lane * 16;
    const int r = off >> 7;
    const int s = (off >> 4) & 7;
    bptr[i] = Wt + (size_t)(n0 + r) * K + (s ^ (r & 7)) * 8;
  }
  // ---- A staging sources ----
  const TIN* aptr[4];               // bf16 path (GLDS16)
  const int arow = tid >> 3;        // fp32 path rows: arow + 32p
  const int acb  = (tid & 7) * 8;   // fp32 col base (8 lanes x 32B = 256B/row)
  #pragma unroll
  for (int i = 0; i < 4; ++i) {
    if constexpr (!AF32) {
      const int off = (w * 4 + i) * 1024 + lane * 16;
      const int r = off >> 7;
      const int s = (off >> 4) & 7;
      aptr[i] = A + (size_t)(m0 + r) * K + (s ^ (r & 7)) * 8;
    } else {
      aptr[i] = nullptr;
    }
  }

  float4 ar[4][2];   // fp32 A in-flight registers

  auto loadA_f32 = [&](int t) {
    #pragma unroll
    for (int p = 0; p < 4; ++p) {
      const float* ap = (const float*)A + (size_t)(m0 + arow + p * 32) * K + t * 64 + acb;
      ar[p][0] = *reinterpret_cast<const float4*>(ap);
      ar[p][1] = *reinterpret_cast<const float4*>(ap + 4);
    }
  };
  auto writeA_f32 = [&]() {
    #pragma unroll
    for (int p = 0; p < 4; ++p) {
      const int row = arow + p * 32;
      uint4 pk;
      pk.x = cvtpk(ar[p][0].x, ar[p][0].y);
      pk.y = cvtpk(ar[p][0].z, ar[p][0].w);
      pk.z = cvtpk(ar[p][1].x, ar[p][1].y);
      pk.w = cvtpk(ar[p][1].z, ar[p][1].w);
      *reinterpret_cast<uint4*>(&As32[row][((tid & 7) * 4) ^ ((row & 7) << 2)]) = pk;
    }
  };
  auto stageA_bf = [&](int t) {
    #pragma unroll
    for (int i = 0; i < 4; ++i)
      GLDS16((const __hip_bfloat16*)aptr[i] + t * 64, (char*)As32 + (w * 4 + i) * 1024);
  };
  auto stageB = [&](int t) {
    #pragma unroll
    for (int i = 0; i < 4; ++i)
      GLDS16(bptr[i] + t * 64, (char*)Bs32 + (w * 4 + i) * 1024);
  };

  // ---- t-invariant LDS read byte-offsets (bf16 layout) ----
  int aoff[4][2], boff[4][2];
  #pragma unroll
  for (int kk = 0; kk < 4; ++kk) {
    #pragma unroll
    for (int mi = 0; mi < 2; ++mi) {
      const int r = wm * 64 + mi * 32 + l31;
      aoff[kk][mi] = r * 128 + (((kk * 2 + hi) ^ (r & 7)) << 4);
    }
    #pragma unroll
    for (int ni = 0; ni < 2; ++ni) {
      const int c = wn * 64 + ni * 32 + l31;
      boff[kk][ni] = c * 128 + (((kk * 2 + hi) ^ (c & 7)) << 4);
    }
  }

  // ---- prologue: stage tile 0 ----
  if constexpr (AF32) { loadA_f32(0); writeA_f32(); }
  else                { stageA_bf(0); }
  stageB(0);
  __syncthreads();

  for (int t = 0; t < NT; ++t) {
    // issue next A global loads early: latency hides under compute(t)
    if (t + 1 < NT) { if constexpr (AF32) loadA_f32(t + 1); }

    // ---- compute tile t ----
    #pragma unroll
    for (int kk = 0; kk < 4; ++kk) {
      bf16x8 af[2], bfv[2];
      #pragma unroll
      for (int mi = 0; mi < 2; ++mi)
        af[mi] = *reinterpret_cast<const bf16x8*>((const char*)As32 + aoff[kk][mi]);
      #pragma unroll
      for (int ni = 0; ni < 2; ++ni)
        bfv[ni] = *reinterpret_cast<const bf16x8*>((const char*)Bs32 + boff[kk][ni]);
      __builtin_amdgcn_s_setprio(1);
      #pragma unroll
      for (int mi = 0; mi < 2; ++mi)
        #pragma unroll
        for (int ni = 0; ni < 2; ++ni)
          acc[mi][ni] = __builtin_amdgcn_mfma_f32_32x32x16_bf16(af[mi], bfv[ni], acc[mi][ni], 0, 0, 0);
      __builtin_amdgcn_s_setprio(0);
    }
    __syncthreads();   // all reads of tile t done

    if (t + 1 < NT) {
      if constexpr (AF32) writeA_f32();
      else                stageA_bf(t + 1);
      stageB(t + 1);
      __syncthreads(); // publish tile t+1
    }
  }

  // ---- epilogue: D col = lane&31, row = (r&3) + 8*(r>>2) + 4*hi ----
  #pragma unroll
  for (int ni = 0; ni < 2; ++ni) {
    const int col = n0 + wn * 64 + ni * 32 + l31;
    const float bv = bias[col];
    #pragma unroll
    for (int mi = 0; mi < 2; ++mi) {
      #pragma unroll
      for (int g = 0; g < 4; ++g)
        #pragma unroll
        for (int e = 0; e < 4; ++e) {
          const int row = m0 + wm * 64 + mi * 32 + g * 8 + hi * 4 + e;
          const float val = acc[mi][ni][g * 4 + e] + bv;
          if constexpr (sizeof(TOUT) == 2)
            C[(size_t)row * DIM + col] = __float2bfloat16(val);
          else
            C[(size_t)row * DIM + col] = val;
        }
    }
  }
}

// ---------------------------------------------------------------------------
// Flash attention (round-7 verified: static-max softmax, QB=256, 512 blocks).
// ---------------------------------------------------------------------------
__global__ __launch_bounds__(256, 2)
void flash_attn(const __hip_bfloat16* __restrict__ Qb,
                const __hip_bfloat16* __restrict__ Kb,
                const __hip_bfloat16* __restrict__ Vb,
                __hip_bfloat16* __restrict__ Ob)
{
  __shared__ __align__(16) u32 Ks32[2][64][32];
  __shared__ __align__(16) u32 Vt32[2][64][32];

  const int id  = blockIdx.x;
  const int xcd = id & 7;
  const int r_  = id >> 3;
  const int qb  = r_ & 7;
  const int hh  = (r_ >> 3) & 1;
  const int b   = r_ >> 4;
  const int h   = xcd + 8 * hh;

  const int tid = threadIdx.x, lane = tid & 63, wv = tid >> 6;
  const int l31 = lane & 31, hi = lane >> 5;

  const size_t headoff = (size_t)h * HDIM;
  const int q0 = b * SEQ + qb * 256 + wv * 64;

  bf16x8 qf[2][4];
  #pragma unroll
  for (int qh = 0; qh < 2; ++qh)
    #pragma unroll
    for (int dk = 0; dk < 4; ++dk)
      qf[qh][dk] = *reinterpret_cast<const bf16x8*>(
        &Qb[(size_t)(q0 + qh * 32 + l31) * DIM + headoff + dk * 16 + hi * 8]);

  f32x16 accO[2][2] = {};
  float l_run[2] = {0.f, 0.f};

  const int skey = tid >> 2;
  const int sdq  = tid & 3;
  const int vkp  = tid >> 3;
  const int vdb  = tid & 7;
  const size_t kbase = (size_t)b * SEQ * DIM + headoff;

  uint4 kst[2], vst[2];
  auto load_t = [&](int t) {
    const int kb = t * 64;
    const __hip_bfloat16* kp_ = &Kb[kbase + (size_t)(kb + skey) * DIM + sdq * 16];
    kst[0] = *reinterpret_cast<const uint4*>(kp_);
    kst[1] = *reinterpret_cast<const uint4*>(kp_ + 8);
    const __hip_bfloat16* vp_ = &Vb[kbase + (size_t)(kb + vkp * 2) * DIM + vdb * 8];
    vst[0] = *reinterpret_cast<const uint4*>(vp_);
    vst[1] = *reinterpret_cast<const uint4*>(vp_ + DIM);
  };
  auto store_t = [&](int bb) {
    const int sk = swz4(skey);
    *reinterpret_cast<uint4*>(&Ks32[bb][skey][(sdq * 8 + 0) ^ sk]) = kst[0];
    *reinterpret_cast<uint4*>(&Ks32[bb][skey][(sdq * 8 + 4) ^ sk]) = kst[1];
    const unsigned short* a  = (const unsigned short*)&vst[0];
    const unsigned short* bv = (const unsigned short*)&vst[1];
    #pragma unroll
    for (int j = 0; j < 8; ++j) {
      const int row = vdb * 8 + j;
      Vt32[bb][row][vkp ^ swz4(row)] = (u32)a[j] | ((u32)bv[j] << 16);
    }
  };

  load_t(0); store_t(0); __syncthreads();

  const float C1 = 0.125f * 1.44269504f;

  for (int t = 0; t < SEQ / 64; ++t) {
    const int bb = t & 1;
    if (t < SEQ / 64 - 1) load_t(t + 1);

    f32x16 sacc[2][2] = {};
    __builtin_amdgcn_s_setprio(1);
    #pragma unroll
    for (int kt = 0; kt < 2; ++kt) {
      const int row = kt * 32 + l31;
      const int sk = swz4(row);
      #pragma unroll
      for (int dk = 0; dk < 4; ++dk) {
        bf16x8 kf = *reinterpret_cast<const bf16x8*>(&Ks32[bb][row][(dk * 8 + hi * 4) ^ sk]);
        sacc[0][kt] = __builtin_amdgcn_mfma_f32_32x32x16_bf16(kf, qf[0][dk], sacc[0][kt], 0, 0, 0);
        sacc[1][kt] = __builtin_amdgcn_mfma_f32_32x32x16_bf16(kf, qf[1][dk], sacc[1][kt], 0, 0, 0);
      }
    }
    __builtin_amdgcn_s_setprio(0);

    u32 pf[2][4][4];
    #pragma unroll
    for (int qh = 0; qh < 2; ++qh) {
      #pragma unroll
      for (int kt = 0; kt < 2; ++kt)
        #pragma unroll
        for (int r2 = 0; r2 < 16; ++r2)
          sacc[qh][kt][r2] = __builtin_amdgcn_exp2f(sacc[qh][kt][r2] * C1);

      f32x16 ps = sacc[qh][0] + sacc[qh][1];
      float s8[8];
      #pragma unroll
      for (int i = 0; i < 8; ++i) s8[i] = ps[i] + ps[i + 8];
      float rs = ((s8[0] + s8[1]) + (s8[2] + s8[3])) + ((s8[4] + s8[5]) + (s8[6] + s8[7]));
      rs += __shfl_xor(rs, 32);
      l_run[qh] += rs;

#define MAKE_PF(DST, P, B) do {                                            \
      u32 x1 = cvtpk(P[B+0], P[B+1]);                                      \
      u32 y1 = cvtpk(P[B+4], P[B+5]);                                      \
      u32 x2 = cvtpk(P[B+2], P[B+3]);                                      \
      u32 y2 = cvtpk(P[B+6], P[B+7]);                                      \
      auto s1 = __builtin_amdgcn_permlane32_swap(x1, y1, false, false);    \
      auto s2 = __builtin_amdgcn_permlane32_swap(x2, y2, false, false);    \
      DST[0] = (u32)s1[0]; DST[1] = (u32)s2[0];                            \
      DST[2] = (u32)s1[1]; DST[3] = (u32)s2[1];                            \
    } while (0)
      MAKE_PF(pf[qh][0], sacc[qh][0], 0);
      MAKE_PF(pf[qh][1], sacc[qh][0], 8);
      MAKE_PF(pf[qh][2], sacc[qh][1], 0);
      MAKE_PF(pf[qh][3], sacc[qh][1], 8);
#undef MAKE_PF
    }

    __builtin_amdgcn_s_setprio(1);
    #pragma unroll
    for (int dt = 0; dt < 2; ++dt) {
      const int row = dt * 32 + l31;
      const int sk = swz4(row);
      #pragma unroll
      for (int kf = 0; kf < 4; ++kf) {
        bf16x8 vf = *reinterpret_cast<const bf16x8*>(&Vt32[bb][row][(kf * 8 + hi * 4) ^ sk]);
        #pragma unroll
        for (int qh = 0; qh < 2; ++qh) {
          union { u32 u[4]; bf16x8 v; } pu;
          pu.u[0] = pf[qh][kf][0]; pu.u[1] = pf[qh][kf][1];
          pu.u[2] = pf[qh][kf][2]; pu.u[3] = pf[qh][kf][3];
          accO[qh][dt] = __builtin_amdgcn_mfma_f32_32x32x16_bf16(vf, pu.v, accO[qh][dt], 0, 0, 0);
        }
      }
    }
    __builtin_amdgcn_s_setprio(0);

    if (t < SEQ / 64 - 1) store_t(bb ^ 1);
    __syncthreads();
  }

  #pragma unroll
  for (int qh = 0; qh < 2; ++qh) {
    const float inv = 1.f / l_run[qh];
    const size_t rowbase = (size_t)(q0 + qh * 32 + l31) * DIM + headoff;
    #pragma unroll
    for (int dt = 0; dt < 2; ++dt)
      #pragma unroll
      for (int g = 0; g < 4; ++g) {
        ushort4 o;
        o.x = f2bfu(accO[qh][dt][g * 4 + 0] * inv);
        o.y = f2bfu(accO[qh][dt][g * 4 + 1] * inv);
        o.z = f2bfu(accO[qh][dt][g * 4 + 2] * inv);
        o.w = f2bfu(accO[qh][dt][g * 4 + 3] * inv);
        *reinterpret_cast<ushort4*>(&Ob[rowbase + dt * 32 + g * 8 + hi * 4]) = o;
      }
  }
}

// ---------------------------------------------------------------------------
extern "C" void kernel_launch(void* const* d_in, const int* in_sizes, int n_in,
                              void* d_out, int out_size, void* d_ws, size_t ws_size,
                              hipStream_t stream)
{
  const float* q  = (const float*)d_in[0];
  const float* k  = (const float*)d_in[1];
  const float* v  = (const float*)d_in[2];
  const float* wq = (const float*)d_in[3];
  const float* bq = (const float*)d_in[4];
  const float* wk = (const float*)d_in[5];
  const float* bk = (const float*)d_in[6];
  const float* wv = (const float*)d_in[7];
  const float* bv = (const float*)d_in[8];
  const float* wo = (const float*)d_in[9];
  const float* bo = (const float*)d_in[10];

  const size_t MN = (size_t)BATCH * SEQ * DIM;   // 8388608
  const size_t KK = (size_t)DIM * DIM;           // 1048576

  __hip_bfloat16* Qb = (__hip_bfloat16*)d_ws;
  __hip_bfloat16* Kb = Qb + MN;
  __hip_bfloat16* Vb = Kb + MN;
  __hip_bfloat16* S3 = Vb + MN;     // 4th 16MB slot
  __hip_bfloat16* WtQ = S3;         // weights live here until attention
  __hip_bfloat16* WtK = S3 + KK;
  __hip_bfloat16* WtV = S3 + 2 * KK;
  __hip_bfloat16* Ob  = S3;         // attention output overwrites Wt (dead)
  __hip_bfloat16* WtO = (__hip_bfloat16*)d_ws;  // into Qb slot after attention

  wtrans<<<768, 256, 0, stream>>>(wq, wk, wv, WtQ, WtK, WtV);

  gemm1ph<float, __hip_bfloat16, 3><<<1536, 256, 0, stream>>>(
      q, k, v, WtQ, WtK, WtV, bq, bk, bv, Qb, Kb, Vb);

  flash_attn<<<512, 256, 0, stream>>>(Qb, Kb, Vb, Ob);

  wtrans<<<256, 256, 0, stream>>>(wo, wo, wo, WtO, WtO, WtO);

  gemm1ph<__hip_bfloat16, float, 1><<<512, 256, 0, stream>>>(
      Ob, Ob, Ob, WtO, WtO, WtO, bo, bo, bo,
      (float*)d_out, (float*)d_out, (float*)d_out);
}